// Round 2
// baseline (309.227 us; speedup 1.0000x reference)
//
#include <hip/hip_runtime.h>
#include <hip/hip_bf16.h>
#include <cstdint>

// Problem constants: b=2, dim=192, heads=6, ch=32, h=w=48, n=2304
#define NSP   2304
#define NT    144            // 2304/16 n-tiles
#define ATTN_ELEMS 63700992  // 2*6*2304*2304

typedef __attribute__((ext_vector_type(8))) __bf16 bf16x8;   // MFMA A/B frag (4 VGPRs)
typedef __attribute__((ext_vector_type(4))) float  float4v;  // MFMA C/D frag

// round-to-nearest-even float -> bf16 bits
__device__ __forceinline__ unsigned short f2bf(float f) {
  union { float f; unsigned int u; } v; v.f = f;
  unsigned int u = v.u;
  unsigned int r = u + 0x7FFFu + ((u >> 16) & 1u);
  return (unsigned short)(r >> 16);
}

__device__ __forceinline__ float bf2f(unsigned int bits16) {
  union { unsigned int u; float f; } v; v.u = bits16 << 16; return v.f;
}

// ---------------------------------------------------------------------------
// Kernel 1: pack weights (M=576 = [wq;wk;wv]) and x into MFMA fragment layouts
//   A-frag layout: elem jj of lane -> [m = lane&15][k = (lane>>4)*8 + jj]
//   B-frag layout: elem jj of lane -> [k = (lane>>4)*8 + jj][n = lane&15]
// Wp: [36 mtiles][6 kchunks][64 lanes][8]   Xp: [b][144 ntiles][6 kchunks][64][8]
// ---------------------------------------------------------------------------
__global__ __launch_bounds__(256) void prep_pack(
    const float* __restrict__ wq, const float* __restrict__ wk,
    const float* __restrict__ wv, const float* __restrict__ x,
    unsigned short* __restrict__ Wp, unsigned short* __restrict__ Xp)
{
  int t = blockIdx.x * 256 + threadIdx.x;      // 486*256 = 124416 = 1944 groups
  int lane = t & 63;
  int g = t >> 6;
  int quad = lane >> 4, col = lane & 15;
  union { int4 v; unsigned short u[8]; } o;
  if (g < 216) {                               // W: 36*6 groups
    int mt = g / 6, kc = g % 6;
    int oo = mt * 16 + col;
    int c0 = kc * 32 + quad * 8;
    const float* w = (oo < 192) ? (wq + (size_t)oo * 192)
                   : (oo < 384) ? (wk + (size_t)(oo - 192) * 192)
                                : (wv + (size_t)(oo - 384) * 192);
#pragma unroll
    for (int jj = 0; jj < 8; ++jj) o.u[jj] = f2bf(w[c0 + jj]);
    ((int4*)Wp)[(size_t)g * 64 + lane] = o.v;
  } else {                                     // X: 2*144*6 groups
    int gx = g - 216;
    int kc = gx % 6;
    int bnt = gx / 6;                          // b*144 + nt
    int b = bnt / 144;
    int n = (bnt % 144) * 16 + col;
    int c0 = kc * 32 + quad * 8;
    const float* xp = x + ((size_t)b * 192 + c0) * NSP + n;
#pragma unroll
    for (int jj = 0; jj < 8; ++jj) o.u[jj] = f2bf(xp[(size_t)jj * NSP]);
    ((int4*)Xp)[(size_t)gx * 64 + lane] = o.v;
  }
}

// ---------------------------------------------------------------------------
// Kernel 2: MFMA projection GEMM: out[o,n] = sum_c Wall[o,c] x[b,c,n]
//   M=576 (3 weights), K=192 (6 chunks of 32), N=2304. Per wave: 16x64 tile.
//   o<192 -> q (ws), <384 -> k (ws), else v (directly to d_out region 1).
//   v stores are nontemporal (never re-read by this chain).
// ---------------------------------------------------------------------------
__global__ __launch_bounds__(256) void proj_mfma(
    const bf16x8* __restrict__ Wp, const bf16x8* __restrict__ Xp,
    float* __restrict__ qws, float* __restrict__ kws, float* __restrict__ vout)
{
  int lane = threadIdx.x & 63, w = threadIdx.x >> 6;
  int ng = blockIdx.x * 4 + w;                 // 0..35 (groups of 4 ntiles)
  int mt = blockIdx.y;                         // 0..35
  int b  = blockIdx.z;                         // 0..1
  int nt0 = ng * 4;
  float4v acc0 = {0.f,0.f,0.f,0.f};
  float4v acc1 = acc0, acc2 = acc0, acc3 = acc0;
#pragma unroll
  for (int kc = 0; kc < 6; ++kc) {
    bf16x8 a = Wp[(size_t)(mt * 6 + kc) * 64 + lane];
    const bf16x8* xb = Xp + (size_t)((b * 144 + nt0) * 6 + kc) * 64 + lane;
    acc0 = __builtin_amdgcn_mfma_f32_16x16x32_bf16(a, xb[0],    acc0, 0, 0, 0);
    acc1 = __builtin_amdgcn_mfma_f32_16x16x32_bf16(a, xb[384],  acc1, 0, 0, 0);
    acc2 = __builtin_amdgcn_mfma_f32_16x16x32_bf16(a, xb[768],  acc2, 0, 0, 0);
    acc3 = __builtin_amdgcn_mfma_f32_16x16x32_bf16(a, xb[1152], acc3, 0, 0, 0);
  }
  int quad = lane >> 4, col = lane & 15;
  int o0 = mt * 16 + quad * 4;                 // C/D layout: row = quad*4+reg
  float4v acc[4] = {acc0, acc1, acc2, acc3};
  if (mt < 24) {                               // q,k: re-read soon, keep cached
    float* dst = (mt < 12) ? (qws + ((size_t)b * 192 + o0) * NSP)
                           : (kws + ((size_t)b * 192 + (o0 - 192)) * NSP);
#pragma unroll
    for (int tt = 0; tt < 4; ++tt)
#pragma unroll
      for (int r = 0; r < 4; ++r)
        dst[(size_t)r * NSP + (nt0 + tt) * 16 + col] = acc[tt][r];
  } else {                                     // v: final output, stream it
    float* dst = vout + ((size_t)b * 192 + (o0 - 384)) * NSP;
#pragma unroll
    for (int tt = 0; tt < 4; ++tt)
#pragma unroll
      for (int r = 0; r < 4; ++r)
        __builtin_nontemporal_store(acc[tt][r],
            dst + (size_t)r * NSP + (nt0 + tt) * 16 + col);
  }
}

// ---------------------------------------------------------------------------
// Kernel 3: per-row sum of squares over n -> inv_norm = 1/max(||row||, 1e-12)
//   rows 0..383 = q (b*192+o), 384..767 = k
// ---------------------------------------------------------------------------
__global__ __launch_bounds__(256) void rownorm(
    const float* __restrict__ qws, const float* __restrict__ kws,
    float* __restrict__ inv)
{
  int r = blockIdx.x;                          // 0..767
  const float* src = (r < 384) ? (qws + (size_t)r * NSP)
                               : (kws + (size_t)(r - 384) * NSP);
  float s = 0.f;
#pragma unroll
  for (int i = 0; i < 9; ++i) { float v = src[threadIdx.x + 256 * i]; s += v * v; }
#pragma unroll
  for (int off = 32; off > 0; off >>= 1) s += __shfl_down(s, off);
  __shared__ float ls[4];
  if ((threadIdx.x & 63) == 0) ls[threadIdx.x >> 6] = s;
  __syncthreads();
  if (threadIdx.x == 0) {
    float tot = ls[0] + ls[1] + ls[2] + ls[3];
    inv[r] = 1.0f / fmaxf(sqrtf(tot), 1e-12f);
  }
}

// ---------------------------------------------------------------------------
// Kernel 4: normalize q,k and pack into attention fragment layout (bf16):
//   P[((bh*144 + jt)*64 + lane)*8 + jj] = src[b][h*32 + (lane>>4)*8+jj][jt*16 + (lane&15)] * inv
// One block = 32ch x 64n tile, LDS transpose, 16B coalesced stores.
// ---------------------------------------------------------------------------
__global__ __launch_bounds__(256) void packqk(
    const float* __restrict__ qws, const float* __restrict__ kws,
    const float* __restrict__ inv,
    unsigned short* __restrict__ Qp, unsigned short* __restrict__ Kp)
{
  int which = blockIdx.z;                      // 0=q, 1=k
  int bh = blockIdx.y;                         // 0..11
  int nc = blockIdx.x;                         // 0..35 (64-wide n chunks)
  const float* src = which ? kws : qws;
  const float* ivp = inv + which * 384;
  int b = bh / 6, h = bh % 6;
  __shared__ float xs[32][65];
  int t = threadIdx.x;
  const float* base = src + ((size_t)b * 192 + h * 32) * NSP + nc * 64;
#pragma unroll
  for (int i = 0; i < 8; ++i) {
    int idx = t + 256 * i;                     // 2048 = 32x64
    int ch = idx >> 6, nl = idx & 63;
    xs[ch][nl] = base[(size_t)ch * NSP + nl] * ivp[b * 192 + h * 32 + ch];
  }
  __syncthreads();
  int jl = t >> 6, lane = t & 63, quad = lane >> 4, col = lane & 15;
  int jt = nc * 4 + jl;
  union { int4 v; unsigned short u[8]; } o;
#pragma unroll
  for (int jj = 0; jj < 8; ++jj) o.u[jj] = f2bf(xs[quad * 8 + jj][jl * 16 + col]);
  int4* dst = (int4*)(which ? Kp : Qp);
  dst[(size_t)(bh * 144 + jt) * 64 + lane] = o.v;
}

// ---------------------------------------------------------------------------
// Kernel 5: attention. Block = one (bh, itile=16 n-rows), 512 threads = 8
// waves, each wave owns 18 jtiles (m-direction).
//
// acc = mfma(Q_tile, K_tile): lane(quad,col) reg r holds
//     S[n = itile*16 + col][m = jt*16 + quad*4 + r]
// exp(S*T) cached as packed bf16 in registers; pass 2 = unpack/scale/store.
// Output stores are NONTEMPORAL: the 255 MB store stream must not evict the
// ~300 KB Qp/Kp per-bh working set from L2 (re-read by 144 blocks per bh).
// ---------------------------------------------------------------------------
__global__ __launch_bounds__(512) void attn_kernel(
    const bf16x8* __restrict__ Qp, const bf16x8* __restrict__ Kp,
    const float* __restrict__ temp, float* __restrict__ out)
{
  int lane = threadIdx.x & 63, w = threadIdx.x >> 6;   // 8 waves
  int itile = blockIdx.x;                      // 0..143
  int bh = blockIdx.y;                         // 0..11
  float T = temp[bh % 6];
  // K tile for this block's 16 n-rows: used as B operand (fixed all iters)
  bf16x8 kf = Kp[((size_t)bh * NT + itile) * 64 + lane];
  const bf16x8* qb = Qp + (size_t)bh * NT * 64 + lane;
  int jt0 = w * 18;

  unsigned int ec[36];                         // 18 jt x 4 exps packed bf16
  float s = 0.f;
#pragma unroll
  for (int u = 0; u < 18; ++u) {
    bf16x8 qf = qb[(size_t)(jt0 + u) * 64];
    float4v acc = {0.f,0.f,0.f,0.f};
    acc = __builtin_amdgcn_mfma_f32_16x16x32_bf16(qf, kf, acc, 0, 0, 0);
    float e0 = __expf(acc[0] * T);
    float e1 = __expf(acc[1] * T);
    float e2 = __expf(acc[2] * T);
    float e3 = __expf(acc[3] * T);
    s += (e0 + e1) + (e2 + e3);
    ec[2*u]   = (unsigned int)f2bf(e0) | ((unsigned int)f2bf(e1) << 16);
    ec[2*u+1] = (unsigned int)f2bf(e2) | ((unsigned int)f2bf(e3) << 16);
  }
  // per-lane s covers this wave's jt range, its quad's 4 m, for n=col.
  // reduce across the 4 quads (lanes col, col+16, col+32, col+48):
  s += __shfl_xor(s, 16);
  s += __shfl_xor(s, 32);
  __shared__ float ls[8][16];
  if (lane < 16) ls[w][lane] = s;
  __syncthreads();
  int col = lane & 15, quad = lane >> 4;
  float tot = 0.f;
#pragma unroll
  for (int ww = 0; ww < 8; ++ww) tot += ls[ww][col];
  float inv = 1.0f / tot;

  // pass 2: unpack cached exps, scale, nontemporal dwordx4 store.
  // row n = itile*16+col, cols m = jt*16 + quad*4 + (0..3)
  float* ob = out + (size_t)bh * NSP * NSP
            + (size_t)(itile * 16 + col) * NSP + quad * 4;
#pragma unroll
  for (int u = 0; u < 18; ++u) {
    unsigned int p0 = ec[2*u], p1 = ec[2*u+1];
    float4v o4;
    o4[0] = bf2f(p0 & 0xffffu) * inv;
    o4[1] = bf2f(p0 >> 16)     * inv;
    o4[2] = bf2f(p1 & 0xffffu) * inv;
    o4[3] = bf2f(p1 >> 16)     * inv;
    __builtin_nontemporal_store(o4, (float4v*)(ob + (size_t)(jt0 + u) * 16));
  }
}

extern "C" void kernel_launch(void* const* d_in, const int* in_sizes, int n_in,
                              void* d_out, int out_size, void* d_ws, size_t ws_size,
                              hipStream_t stream) {
  const float* x    = (const float*)d_in[0];   // [2][192][2304]
  const float* wq   = (const float*)d_in[1];   // [192][192]
  const float* wk   = (const float*)d_in[2];
  const float* wv   = (const float*)d_in[3];
  const float* temp = (const float*)d_in[4];   // [6]

  float* attn_out = (float*)d_out;                     // [2][6][2304][2304]
  float* vout     = attn_out + (size_t)ATTN_ELEMS;     // [2][6][32][2304]

  // workspace carve-up (~12.6 MB total, all 16B-aligned)
  float* qws = (float*)d_ws;                   // 884736 f32
  float* kws = qws + 884736;                   // 884736 f32
  float* inv = kws + 884736;                   // 768 f32
  unsigned short* Wp = (unsigned short*)(inv + 768);   // 110592 bf16
  unsigned short* Xp = Wp + 110592;                    // 884736 bf16
  unsigned short* Qp = Xp + 884736;                    // 884736 bf16
  unsigned short* Kp = Qp + 884736;                    // 884736 bf16

  hipLaunchKernelGGL(prep_pack, dim3(486), dim3(256), 0, stream,
                     wq, wk, wv, x, Wp, Xp);
  hipLaunchKernelGGL(proj_mfma, dim3(9, 36, 2), dim3(256), 0, stream,
                     (const bf16x8*)Wp, (const bf16x8*)Xp, qws, kws, vout);
  hipLaunchKernelGGL(rownorm, dim3(768), dim3(256), 0, stream, qws, kws, inv);
  hipLaunchKernelGGL(packqk, dim3(36, 12, 2), dim3(256), 0, stream,
                     qws, kws, inv, Qp, Kp);
  hipLaunchKernelGGL(attn_kernel, dim3(144, 12), dim3(512), 0, stream,
                     (const bf16x8*)Qp, (const bf16x8*)Kp, temp, attn_out);
}

// Round 3
// 277.954 us; speedup vs baseline: 1.1125x; 1.1125x over previous
//
#include <hip/hip_runtime.h>
#include <hip/hip_bf16.h>
#include <cstdint>

// Problem constants: b=2, dim=192, heads=6, ch=32, h=w=48, n=2304
#define NSP   2304
#define NT    144            // 2304/16 n-tiles
#define ATTN_ELEMS 63700992  // 2*6*2304*2304

typedef __attribute__((ext_vector_type(8))) __bf16 bf16x8;   // MFMA A/B frag (4 VGPRs)
typedef __attribute__((ext_vector_type(4))) float  float4v;  // MFMA C/D frag

// round-to-nearest-even float -> bf16 bits
__device__ __forceinline__ unsigned short f2bf(float f) {
  union { float f; unsigned int u; } v; v.f = f;
  unsigned int u = v.u;
  unsigned int r = u + 0x7FFFu + ((u >> 16) & 1u);
  return (unsigned short)(r >> 16);
}

__device__ __forceinline__ float bf2f(unsigned int bits16) {
  union { unsigned int u; float f; } v; v.u = bits16 << 16; return v.f;
}

// ---------------------------------------------------------------------------
// Kernel 1: pack weights (M=576 = [wq;wk;wv]) and x into MFMA fragment layouts
//   A-frag layout: elem jj of lane -> [m = lane&15][k = (lane>>4)*8 + jj]
//   B-frag layout: elem jj of lane -> [k = (lane>>4)*8 + jj][n = lane&15]
// Wp: [36 mtiles][6 kchunks][64 lanes][8]   Xp: [b][144 ntiles][6 kchunks][64][8]
// ---------------------------------------------------------------------------
__global__ __launch_bounds__(256) void prep_pack(
    const float* __restrict__ wq, const float* __restrict__ wk,
    const float* __restrict__ wv, const float* __restrict__ x,
    unsigned short* __restrict__ Wp, unsigned short* __restrict__ Xp)
{
  int t = blockIdx.x * 256 + threadIdx.x;      // 486*256 = 124416 = 1944 groups
  int lane = t & 63;
  int g = t >> 6;
  int quad = lane >> 4, col = lane & 15;
  union { int4 v; unsigned short u[8]; } o;
  if (g < 216) {                               // W: 36*6 groups
    int mt = g / 6, kc = g % 6;
    int oo = mt * 16 + col;
    int c0 = kc * 32 + quad * 8;
    const float* w = (oo < 192) ? (wq + (size_t)oo * 192)
                   : (oo < 384) ? (wk + (size_t)(oo - 192) * 192)
                                : (wv + (size_t)(oo - 384) * 192);
#pragma unroll
    for (int jj = 0; jj < 8; ++jj) o.u[jj] = f2bf(w[c0 + jj]);
    ((int4*)Wp)[(size_t)g * 64 + lane] = o.v;
  } else {                                     // X: 2*144*6 groups
    int gx = g - 216;
    int kc = gx % 6;
    int bnt = gx / 6;                          // b*144 + nt
    int b = bnt / 144;
    int n = (bnt % 144) * 16 + col;
    int c0 = kc * 32 + quad * 8;
    const float* xp = x + ((size_t)b * 192 + c0) * NSP + n;
#pragma unroll
    for (int jj = 0; jj < 8; ++jj) o.u[jj] = f2bf(xp[(size_t)jj * NSP]);
    ((int4*)Xp)[(size_t)gx * 64 + lane] = o.v;
  }
}

// ---------------------------------------------------------------------------
// Kernel 2: MFMA projection GEMM: out[o,n] = sum_c Wall[o,c] x[b,c,n]
//   M=576 (3 weights), K=192 (6 chunks of 32), N=2304. Per wave: 16x64 tile.
//   o<192 -> q (ws), <384 -> k (ws), else v (directly to d_out region 1).
// ---------------------------------------------------------------------------
__global__ __launch_bounds__(256) void proj_mfma(
    const bf16x8* __restrict__ Wp, const bf16x8* __restrict__ Xp,
    float* __restrict__ qws, float* __restrict__ kws, float* __restrict__ vout)
{
  int lane = threadIdx.x & 63, w = threadIdx.x >> 6;
  int ng = blockIdx.x * 4 + w;                 // 0..35 (groups of 4 ntiles)
  int mt = blockIdx.y;                         // 0..35
  int b  = blockIdx.z;                         // 0..1
  int nt0 = ng * 4;
  float4v acc0 = {0.f,0.f,0.f,0.f};
  float4v acc1 = acc0, acc2 = acc0, acc3 = acc0;
#pragma unroll
  for (int kc = 0; kc < 6; ++kc) {
    bf16x8 a = Wp[(size_t)(mt * 6 + kc) * 64 + lane];
    const bf16x8* xb = Xp + (size_t)((b * 144 + nt0) * 6 + kc) * 64 + lane;
    acc0 = __builtin_amdgcn_mfma_f32_16x16x32_bf16(a, xb[0],    acc0, 0, 0, 0);
    acc1 = __builtin_amdgcn_mfma_f32_16x16x32_bf16(a, xb[384],  acc1, 0, 0, 0);
    acc2 = __builtin_amdgcn_mfma_f32_16x16x32_bf16(a, xb[768],  acc2, 0, 0, 0);
    acc3 = __builtin_amdgcn_mfma_f32_16x16x32_bf16(a, xb[1152], acc3, 0, 0, 0);
  }
  int quad = lane >> 4, col = lane & 15;
  int o0 = mt * 16 + quad * 4;                 // C/D layout: row = quad*4+reg
  float* dst;
  if (mt < 12)      dst = qws + ((size_t)b * 192 + o0) * NSP;
  else if (mt < 24) dst = kws + ((size_t)b * 192 + (o0 - 192)) * NSP;
  else              dst = vout + ((size_t)b * 192 + (o0 - 384)) * NSP;
  float4v acc[4] = {acc0, acc1, acc2, acc3};
#pragma unroll
  for (int tt = 0; tt < 4; ++tt)
#pragma unroll
    for (int r = 0; r < 4; ++r)
      dst[(size_t)r * NSP + (nt0 + tt) * 16 + col] = acc[tt][r];
}

// ---------------------------------------------------------------------------
// Kernel 3: per-row sum of squares over n -> inv_norm = 1/max(||row||, 1e-12)
//   rows 0..383 = q (b*192+o), 384..767 = k
// ---------------------------------------------------------------------------
__global__ __launch_bounds__(256) void rownorm(
    const float* __restrict__ qws, const float* __restrict__ kws,
    float* __restrict__ inv)
{
  int r = blockIdx.x;                          // 0..767
  const float* src = (r < 384) ? (qws + (size_t)r * NSP)
                               : (kws + (size_t)(r - 384) * NSP);
  float s = 0.f;
#pragma unroll
  for (int i = 0; i < 9; ++i) { float v = src[threadIdx.x + 256 * i]; s += v * v; }
#pragma unroll
  for (int off = 32; off > 0; off >>= 1) s += __shfl_down(s, off);
  __shared__ float ls[4];
  if ((threadIdx.x & 63) == 0) ls[threadIdx.x >> 6] = s;
  __syncthreads();
  if (threadIdx.x == 0) {
    float tot = ls[0] + ls[1] + ls[2] + ls[3];
    inv[r] = 1.0f / fmaxf(sqrtf(tot), 1e-12f);
  }
}

// ---------------------------------------------------------------------------
// Kernel 4: normalize q,k and pack into attention fragment layout (bf16):
//   P[((bh*144 + jt)*64 + lane)*8 + jj] = src[b][h*32 + (lane>>4)*8+jj][jt*16 + (lane&15)] * inv
// One block = 32ch x 64n tile, LDS transpose, 16B coalesced stores.
// ---------------------------------------------------------------------------
__global__ __launch_bounds__(256) void packqk(
    const float* __restrict__ qws, const float* __restrict__ kws,
    const float* __restrict__ inv,
    unsigned short* __restrict__ Qp, unsigned short* __restrict__ Kp)
{
  int which = blockIdx.z;                      // 0=q, 1=k
  int bh = blockIdx.y;                         // 0..11
  int nc = blockIdx.x;                         // 0..35 (64-wide n chunks)
  const float* src = which ? kws : qws;
  const float* ivp = inv + which * 384;
  int b = bh / 6, h = bh % 6;
  __shared__ float xs[32][65];
  int t = threadIdx.x;
  const float* base = src + ((size_t)b * 192 + h * 32) * NSP + nc * 64;
#pragma unroll
  for (int i = 0; i < 8; ++i) {
    int idx = t + 256 * i;                     // 2048 = 32x64
    int ch = idx >> 6, nl = idx & 63;
    xs[ch][nl] = base[(size_t)ch * NSP + nl] * ivp[b * 192 + h * 32 + ch];
  }
  __syncthreads();
  int jl = t >> 6, lane = t & 63, quad = lane >> 4, col = lane & 15;
  int jt = nc * 4 + jl;
  union { int4 v; unsigned short u[8]; } o;
#pragma unroll
  for (int jj = 0; jj < 8; ++jj) o.u[jj] = f2bf(xs[quad * 8 + jj][jl * 16 + col]);
  int4* dst = (int4*)(which ? Kp : Qp);
  dst[(size_t)(bh * 144 + jt) * 64 + lane] = o.v;
}

// ---------------------------------------------------------------------------
// Kernel 5: attention. Block = one (bh, itile=16 n-rows), 512 threads = 8
// waves. Wave w owns jt = w + 8u (u=0..17), INTERLEAVED so that 2 consecutive
// u across all 8 waves tile 256 contiguous output columns.
//
// acc = mfma(Q_tile, K_tile): lane(quad,col) reg r holds
//     S[n = itile*16 + col][m = jt*16 + quad*4 + r]
// exp(S*T) cached as packed bf16 in registers.
// Pass 2 routes through an LDS transpose so every global store instruction is
// a fully contiguous, 128B-aligned 1KB wave store (complete cache lines).
// Rationale: R0/R1 both stored 64B half-lines and both ran ~2.5x over the
// write floor -> suspected partial-line RMW fetch; full-line stores match the
// fill kernel's 6.4 TB/s pattern.
// ---------------------------------------------------------------------------
__global__ __launch_bounds__(512) void attn_kernel(
    const bf16x8* __restrict__ Qp, const bf16x8* __restrict__ Kp,
    const float* __restrict__ temp, float* __restrict__ out)
{
  int lane = threadIdx.x & 63, w = threadIdx.x >> 6;   // 8 waves
  int itile = blockIdx.x;                      // 0..143
  int bh = blockIdx.y;                         // 0..11
  float T = temp[bh % 6];
  // K tile for this block's 16 n-rows: used as B operand (fixed all iters)
  bf16x8 kf = Kp[((size_t)bh * NT + itile) * 64 + lane];
  const bf16x8* qb = Qp + (size_t)bh * NT * 64 + lane;

  unsigned int ec[36];                         // 18 jt x 4 exps packed bf16
  float s = 0.f;
#pragma unroll
  for (int u = 0; u < 18; ++u) {
    int jt = w + 8 * u;                        // interleaved assignment
    bf16x8 qf = qb[(size_t)jt * 64];
    float4v acc = {0.f,0.f,0.f,0.f};
    acc = __builtin_amdgcn_mfma_f32_16x16x32_bf16(qf, kf, acc, 0, 0, 0);
    float e0 = __expf(acc[0] * T);
    float e1 = __expf(acc[1] * T);
    float e2 = __expf(acc[2] * T);
    float e3 = __expf(acc[3] * T);
    s += (e0 + e1) + (e2 + e3);
    ec[2*u]   = (unsigned int)f2bf(e0) | ((unsigned int)f2bf(e1) << 16);
    ec[2*u+1] = (unsigned int)f2bf(e2) | ((unsigned int)f2bf(e3) << 16);
  }
  // per-lane s covers this wave's 18 jt, its quad's 4 m, for n=col.
  // reduce across the 4 quads (lanes col, col+16, col+32, col+48):
  s += __shfl_xor(s, 16);
  s += __shfl_xor(s, 32);
  __shared__ float ls[8][16];
  if (lane < 16) ls[w][lane] = s;
  __syncthreads();
  int col = lane & 15, quad = lane >> 4;
  float tot = 0.f;
#pragma unroll
  for (int ww = 0; ww < 8; ++ww) tot += ls[ww][col];
  float inv = 1.0f / tot;

  // pass 2: 9 chunks of 256 columns. Each chunk: scale 8 vals/thread into a
  // [16 rows][260] padded LDS tile (write banks evenly spread, reads linear),
  // then each wave streams 2 complete rows as contiguous 1KB dwordx4 stores.
  __shared__ float xs[16][260];                // 16.6 KB, +4 pad keeps 16B align
  float* obase = out + (size_t)bh * NSP * NSP + (size_t)(itile * 16) * NSP;
  for (int c = 0; c < 9; ++c) {
#pragma unroll
    for (int ul = 0; ul < 2; ++ul) {
      int u = 2 * c + ul;                      // jt = w + 8u -> chunk-local col
      unsigned int p0 = ec[2*u], p1 = ec[2*u+1];
      float4v o4;
      o4[0] = bf2f(p0 & 0xffffu) * inv;
      o4[1] = bf2f(p0 >> 16)     * inv;
      o4[2] = bf2f(p1 & 0xffffu) * inv;
      o4[3] = bf2f(p1 >> 16)     * inv;
      *(float4v*)&xs[col][(ul * 8 + w) * 16 + quad * 4] = o4;
    }
    __syncthreads();
#pragma unroll
    for (int rr = 0; rr < 2; ++rr) {
      int row = w + rr * 8;
      float4v o4 = *(const float4v*)&xs[row][lane * 4];
      *(float4v*)(obase + (size_t)row * NSP + c * 256 + lane * 4) = o4;
    }
    __syncthreads();
  }
}

extern "C" void kernel_launch(void* const* d_in, const int* in_sizes, int n_in,
                              void* d_out, int out_size, void* d_ws, size_t ws_size,
                              hipStream_t stream) {
  const float* x    = (const float*)d_in[0];   // [2][192][2304]
  const float* wq   = (const float*)d_in[1];   // [192][192]
  const float* wk   = (const float*)d_in[2];
  const float* wv   = (const float*)d_in[3];
  const float* temp = (const float*)d_in[4];   // [6]

  float* attn_out = (float*)d_out;                     // [2][6][2304][2304]
  float* vout     = attn_out + (size_t)ATTN_ELEMS;     // [2][6][32][2304]

  // workspace carve-up (~12.6 MB total, all 16B-aligned)
  float* qws = (float*)d_ws;                   // 884736 f32
  float* kws = qws + 884736;                   // 884736 f32
  float* inv = kws + 884736;                   // 768 f32
  unsigned short* Wp = (unsigned short*)(inv + 768);   // 110592 bf16
  unsigned short* Xp = Wp + 110592;                    // 884736 bf16
  unsigned short* Qp = Xp + 884736;                    // 884736 bf16
  unsigned short* Kp = Qp + 884736;                    // 884736 bf16

  hipLaunchKernelGGL(prep_pack, dim3(486), dim3(256), 0, stream,
                     wq, wk, wv, x, Wp, Xp);
  hipLaunchKernelGGL(proj_mfma, dim3(9, 36, 2), dim3(256), 0, stream,
                     (const bf16x8*)Wp, (const bf16x8*)Xp, qws, kws, vout);
  hipLaunchKernelGGL(rownorm, dim3(768), dim3(256), 0, stream, qws, kws, inv);
  hipLaunchKernelGGL(packqk, dim3(36, 12, 2), dim3(256), 0, stream,
                     qws, kws, inv, Qp, Kp);
  hipLaunchKernelGGL(attn_kernel, dim3(144, 12), dim3(512), 0, stream,
                     (const bf16x8*)Qp, (const bf16x8*)Kp, temp, attn_out);
}